// Round 1
// baseline (253.859 us; speedup 1.0000x reference)
//
#include <hip/hip_runtime.h>
#include <cstddef>

#define B_   4
#define NQ_  8192
#define C_   256
#define H_   128
#define W_   128
#define HW_  (H_ * W_)
#define NH_  8
#define NP_  4
#define HD_  32

// ---------------------------------------------------------------------------
// Generic fp32 GEMM: 128x128 tile, 8x8 micro-tile per thread, K-chunk 8.
// BMODE 0: plain row-major B0[k*N + n], bias0[n]
// BMODE 1: composite projection matrix (96 real cols, padded to 128):
//          n<64 -> W_off[k*64+n] / b_off[n]; 64<=n<96 -> W_attn[k*32+n-64] /
//          b_attn[n-64]; n>=96 -> zero (not stored)
// OMODE 0: plain C[m*ldc + n]
// OMODE 1: value-permute store: m = b*HW + pix, n = h*HD + d
//          -> C[((b*NH + h)*HW + pix)*HD + d]
// ---------------------------------------------------------------------------
template<int BMODE, int OMODE>
__global__ __launch_bounds__(256, 4)
void gemm_f32_128(const float* __restrict__ A,
                  const float* __restrict__ B0, const float* __restrict__ B1,
                  const float* __restrict__ bias0, const float* __restrict__ bias1,
                  float* __restrict__ C,
                  int K, int N, int ldc)
{
    __shared__ float As[8][128];
    __shared__ float Bs[8][128];
    const int tid = threadIdx.x;
    const int m0 = blockIdx.x * 128;
    const int n0 = blockIdx.y * 128;
    const int tx = tid & 15;   // 0..15 -> n micro
    const int ty = tid >> 4;   // 0..15 -> m micro
    float acc[8][8];
#pragma unroll
    for (int i = 0; i < 8; ++i)
#pragma unroll
        for (int j = 0; j < 8; ++j) acc[i][j] = 0.f;

    const int arow = tid >> 1;          // 0..127
    const int ak   = (tid & 1) * 4;     // 0 or 4
    const int bk   = tid >> 5;          // 0..7
    const int bn   = (tid & 31) * 4;    // 0..124

    for (int k0 = 0; k0 < K; k0 += 8) {
        float4 av = *(const float4*)&A[(size_t)(m0 + arow) * K + (k0 + ak)];
        float4 bv;
        if (BMODE == 0) {
            bv = *(const float4*)&B0[(size_t)(k0 + bk) * N + (n0 + bn)];
        } else {
            const int c = n0 + bn;
            if (c + 3 < 64)  bv = *(const float4*)&B0[(size_t)(k0 + bk) * 64 + c];
            else if (c < 96) bv = *(const float4*)&B1[(size_t)(k0 + bk) * 32 + (c - 64)];
            else             bv = make_float4(0.f, 0.f, 0.f, 0.f);
        }
        __syncthreads();   // previous chunk's compute done before overwrite
        As[ak + 0][arow] = av.x;
        As[ak + 1][arow] = av.y;
        As[ak + 2][arow] = av.z;
        As[ak + 3][arow] = av.w;
        *(float4*)&Bs[bk][bn] = bv;
        __syncthreads();
#pragma unroll
        for (int kk = 0; kk < 8; ++kk) {
            float a[8], b[8];
            *(float4*)&a[0] = *(const float4*)&As[kk][ty * 4];
            *(float4*)&a[4] = *(const float4*)&As[kk][64 + ty * 4];
            *(float4*)&b[0] = *(const float4*)&Bs[kk][tx * 4];
            *(float4*)&b[4] = *(const float4*)&Bs[kk][64 + tx * 4];
#pragma unroll
            for (int i = 0; i < 8; ++i)
#pragma unroll
                for (int j = 0; j < 8; ++j)
                    acc[i][j] = fmaf(a[i], b[j], acc[i][j]);
        }
    }

    // epilogue: bias + store
#pragma unroll
    for (int i = 0; i < 8; ++i) {
        const int m = m0 + (i >> 2) * 64 + ty * 4 + (i & 3);
#pragma unroll
        for (int jb = 0; jb < 2; ++jb) {
            const int n = n0 + jb * 64 + tx * 4;
            if (BMODE == 1 && n >= 96) continue;
            float o[4];
#pragma unroll
            for (int jj = 0; jj < 4; ++jj) {
                float bs;
                if (BMODE == 0) bs = bias0[n + jj];
                else            bs = (n + jj < 64) ? bias0[n + jj] : bias1[n + jj - 64];
                o[jj] = acc[i][jb * 4 + jj] + bs;
            }
            if (OMODE == 0) {
                *(float4*)&C[(size_t)m * ldc + n] = *(const float4*)o;
            } else {
                const size_t dst = ((size_t)((m >> 14) * NH_ + (n >> 5))) * (size_t)(HW_ * HD_)
                                 + (size_t)(m & (HW_ - 1)) * HD_ + (n & (HD_ - 1));
                *(float4*)&C[dst] = *(const float4*)o;
            }
        }
    }
}

// ---------------------------------------------------------------------------
// Sampling: one block per query. thread = (h = tid>>5, d = tid&31).
// Reads offattn row (96 floats) + ref point from LDS, does softmax over
// NP=4 (redundant per 32-lane group), 4 bilinear taps, writes samp[q][h*32+d].
// ---------------------------------------------------------------------------
__global__ __launch_bounds__(256)
void sample_kernel(const float* __restrict__ oa,    // [B*NQ, 96]
                   const float* __restrict__ ref,   // [B*NQ, 2]
                   const float* __restrict__ vproj, // [B*NH, HW, HD]
                   float* __restrict__ samp)        // [B*NQ, 256]
{
    __shared__ float s_oa[96];
    __shared__ float s_ref[2];
    const int q = blockIdx.x;
    const int tid = threadIdx.x;
    if (tid < 96) s_oa[tid] = oa[(size_t)q * 96 + tid];
    if (tid < 2)  s_ref[tid] = ref[(size_t)q * 2 + tid];
    __syncthreads();

    const int d = tid & 31;
    const int h = tid >> 5;
    const int b = q >> 13;   // q / NQ_
    const float* vh = vproj + (size_t)(b * NH_ + h) * (HW_ * HD_);

    // softmax over the 4 attention logits of this head
    const float l0 = s_oa[64 + h * 4 + 0];
    const float l1 = s_oa[64 + h * 4 + 1];
    const float l2 = s_oa[64 + h * 4 + 2];
    const float l3 = s_oa[64 + h * 4 + 3];
    const float mx = fmaxf(fmaxf(l0, l1), fmaxf(l2, l3));
    const float e0 = __expf(l0 - mx), e1 = __expf(l1 - mx);
    const float e2 = __expf(l2 - mx), e3 = __expf(l3 - mx);
    const float inv = 1.f / (e0 + e1 + e2 + e3);
    const float aw[4] = { e0 * inv, e1 * inv, e2 * inv, e3 * inv };

    const float rx = s_ref[0], ry = s_ref[1];
    float acc = 0.f;
#pragma unroll
    for (int p = 0; p < 4; ++p) {
        const float ox = s_oa[h * 8 + p * 2 + 0] * (0.1f / (float)W_);
        const float oy = s_oa[h * 8 + p * 2 + 1] * (0.1f / (float)H_);
        const float lx = fminf(fmaxf(rx + ox, 0.f), 1.f);
        const float ly = fminf(fmaxf(ry + oy, 0.f), 1.f);
        const float gx = fminf(fmaxf(lx * (float)W_ - 0.5f, 0.f), (float)(W_ - 1));
        const float gy = fminf(fmaxf(ly * (float)H_ - 0.5f, 0.f), (float)(H_ - 1));
        const float x0f = floorf(gx), y0f = floorf(gy);
        const float fx = gx - x0f, fy = gy - y0f;
        const int x0 = (int)x0f, y0 = (int)y0f;
        const int x1 = min(x0 + 1, W_ - 1), y1 = min(y0 + 1, H_ - 1);
        const float* r0 = vh + (size_t)(y0 * W_) * HD_;
        const float* r1 = vh + (size_t)(y1 * W_) * HD_;
        const float v00 = r0[x0 * HD_ + d];
        const float v10 = r0[x1 * HD_ + d];
        const float v01 = r1[x0 * HD_ + d];
        const float v11 = r1[x1 * HD_ + d];
        const float vx0 = v00 + fx * (v10 - v00);
        const float vx1 = v01 + fx * (v11 - v01);
        acc += aw[p] * (vx0 + fy * (vx1 - vx0));
    }
    samp[(size_t)q * 256 + h * HD_ + d] = acc;
}

// ---------------------------------------------------------------------------
extern "C" void kernel_launch(void* const* d_in, const int* in_sizes, int n_in,
                              void* d_out, int out_size, void* d_ws, size_t ws_size,
                              hipStream_t stream)
{
    const float* query  = (const float*)d_in[0];
    const float* refpt  = (const float*)d_in[1];
    const float* value  = (const float*)d_in[2];
    const float* W_off  = (const float*)d_in[3];
    const float* b_off  = (const float*)d_in[4];
    const float* W_attn = (const float*)d_in[5];
    const float* b_attn = (const float*)d_in[6];
    const float* W_val  = (const float*)d_in[7];
    const float* b_val  = (const float*)d_in[8];
    const float* W_out  = (const float*)d_in[9];
    const float* b_out  = (const float*)d_in[10];
    float* out = (float*)d_out;

    char* ws = (char*)d_ws;
    float* vproj = (float*)ws;                                        // 64 MiB
    float* samp  = (float*)(ws + (size_t)64 * 1024 * 1024);           // 32 MiB
    float* oa    = (float*)(ws + (size_t)96 * 1024 * 1024);           // 12 MiB

    // K1: vproj[b,h,pix,d] = (value @ W_val + b_val) permuted
    gemm_f32_128<0, 1><<<dim3((B_ * HW_) / 128, C_ / 128), 256, 0, stream>>>(
        value, W_val, nullptr, b_val, nullptr, vproj, C_, C_, C_);

    // K2a: oa[q, 0:64]=query@W_off+b_off ; oa[q, 64:96]=query@W_attn+b_attn
    gemm_f32_128<1, 0><<<dim3((B_ * NQ_) / 128, 1), 256, 0, stream>>>(
        query, W_off, W_attn, b_off, b_attn, oa, C_, C_, 96);

    // K2b: bilinear deformable sampling -> samp[q, h*32+d]
    sample_kernel<<<B_ * NQ_, 256, 0, stream>>>(oa, refpt, vproj, samp);

    // K3: out = samp @ W_out + b_out
    gemm_f32_128<0, 0><<<dim3((B_ * NQ_) / 128, C_ / 128), 256, 0, stream>>>(
        samp, W_out, nullptr, b_out, nullptr, out, C_, C_, C_);
}

// Round 2
// 111.271 us; speedup vs baseline: 2.2815x; 2.2815x over previous
//
#include <hip/hip_runtime.h>
#include <cstddef>

#define B_   4
#define NQ_  8192
#define C_   256
#define H_   128
#define W_   128
#define HW_  (H_ * W_)
#define NH_  8
#define NP_  4
#define HD_  32

typedef __attribute__((ext_vector_type(8))) short s16x8;
typedef __attribute__((ext_vector_type(4))) float f32x4;

__device__ __forceinline__ short f2bf(float x) {
    unsigned u = __float_as_uint(x);
    unsigned r = (u + 0x7FFFu + ((u >> 16) & 1u)) >> 16;
    return (short)r;
}
__device__ __forceinline__ float bf2f(short s) {
    return __uint_as_float(((unsigned)(unsigned short)s) << 16);
}
__device__ __forceinline__ void gload_lds16(const void* g, void* l) {
    __builtin_amdgcn_global_load_lds(
        (const __attribute__((address_space(1))) void*)g,
        (__attribute__((address_space(3))) void*)l, 16, 0, 0);
}

// ---------------------------------------------------------------------------
// Prep: build transposed bf16 weights Bt[n][k] (+ composite off|attn matrix
// padded to 128 cols with zeros, and its padded bias).
// grid 640 x 256: block<256 -> BtVal row, <512 -> BtOut row, else BtOA row.
// ---------------------------------------------------------------------------
__global__ void prep_kernel(const float* __restrict__ Wv, const float* __restrict__ Wo,
                            const float* __restrict__ Woff, const float* __restrict__ Wattn,
                            const float* __restrict__ boff, const float* __restrict__ battn,
                            short* __restrict__ BtVal, short* __restrict__ BtOut,
                            short* __restrict__ BtOA, float* __restrict__ biasOA)
{
    const int b = blockIdx.x, t = threadIdx.x;   // t = k index, 0..255
    if (b < 256) {
        const int n = b;
        BtVal[(size_t)n * 256 + t] = f2bf(Wv[(size_t)t * 256 + n]);
    } else if (b < 512) {
        const int n = b - 256;
        BtOut[(size_t)n * 256 + t] = f2bf(Wo[(size_t)t * 256 + n]);
    } else {
        const int n = b - 512;   // 0..127
        float v = (n < 64) ? Woff[(size_t)t * 64 + n]
                           : (n < 96 ? Wattn[(size_t)t * 32 + (n - 64)] : 0.f);
        BtOA[(size_t)n * 256 + t] = f2bf(v);
        if (t == 0) biasOA[n] = (n < 64) ? boff[n] : (n < 96 ? battn[n - 64] : 0.f);
    }
}

// ---------------------------------------------------------------------------
// bf16 MFMA GEMM, K=256 fixed. 128x128 tile, 4 waves (2x2 of 64x64 each),
// BK=32, mfma_f32_16x16x32_bf16. B is pre-transposed bf16 Bt[n][k].
// AMODE 0: A bf16 [M][256], staged via global_load_lds (width 16).
// AMODE 1: A f32  [M][256], reg-staged with fp32->bf16 conversion.
// OMODE 0: f32 C[m*ldc+n]; OMODE 1: bf16 C[m*ldc+n];
// OMODE 2: bf16 vproj-permute C[((b*NH+h)*HW+pix)*HD+d].
// ---------------------------------------------------------------------------
template<int AMODE, int OMODE>
__global__ __launch_bounds__(256)
void gemm_mfma(const void* __restrict__ Ap, const short* __restrict__ Bt,
               const float* __restrict__ bias, void* __restrict__ Cp, int ldc)
{
    __shared__ short As[128 * 32];
    __shared__ short Bs[128 * 32];
    const int tid = threadIdx.x;
    const int l = tid & 63;
    const int w = tid >> 6;          // wave 0..3
    const int wm = w >> 1, wn = w & 1;
    const int m0 = blockIdx.x * 128;
    const int n0 = blockIdx.y * 128;

    f32x4 acc[4][4];
#pragma unroll
    for (int i = 0; i < 4; ++i)
#pragma unroll
        for (int j = 0; j < 4; ++j) acc[i][j] = (f32x4)0.f;

    const int frag_r = l & 15;       // row (A) / col (B) within fragment
    const int kslot  = (l >> 4) * 8; // k offset (shorts)

    for (int k0 = 0; k0 < 256; k0 += 32) {
        __syncthreads();   // previous step's ds_reads done before overwrite
        // ---- stage B tile (always bf16 global_load_lds) ----
#pragma unroll
        for (int r = 0; r < 2; ++r) {
            const int i = r * 256 + tid;
            const int row = i >> 2, cb = (i & 3) * 8;
            gload_lds16(&Bt[(size_t)(n0 + row) * 256 + k0 + cb],
                        (char*)Bs + r * 4096 + w * 1024);
        }
        // ---- stage A tile ----
        if (AMODE == 0) {
            const short* A16 = (const short*)Ap;
#pragma unroll
            for (int r = 0; r < 2; ++r) {
                const int i = r * 256 + tid;
                const int row = i >> 2, cb = (i & 3) * 8;
                gload_lds16(&A16[(size_t)(m0 + row) * 256 + k0 + cb],
                            (char*)As + r * 4096 + w * 1024);
            }
        } else {
            const float* Af = (const float*)Ap;
            const int row = tid >> 1, half = tid & 1;
            const float* src = &Af[(size_t)(m0 + row) * 256 + k0 + half * 16];
            float4 f0 = ((const float4*)src)[0];
            float4 f1 = ((const float4*)src)[1];
            float4 f2 = ((const float4*)src)[2];
            float4 f3 = ((const float4*)src)[3];
            union { short s[8]; s16x8 v; } p0, p1;
            p0.s[0]=f2bf(f0.x); p0.s[1]=f2bf(f0.y); p0.s[2]=f2bf(f0.z); p0.s[3]=f2bf(f0.w);
            p0.s[4]=f2bf(f1.x); p0.s[5]=f2bf(f1.y); p0.s[6]=f2bf(f1.z); p0.s[7]=f2bf(f1.w);
            p1.s[0]=f2bf(f2.x); p1.s[1]=f2bf(f2.y); p1.s[2]=f2bf(f2.z); p1.s[3]=f2bf(f2.w);
            p1.s[4]=f2bf(f3.x); p1.s[5]=f2bf(f3.y); p1.s[6]=f2bf(f3.z); p1.s[7]=f2bf(f3.w);
            *(s16x8*)&As[row * 32 + half * 16]     = p0.v;
            *(s16x8*)&As[row * 32 + half * 16 + 8] = p1.v;
        }
        __syncthreads();   // drains vmcnt + lgkm: tiles visible
        // ---- compute ----
        s16x8 a[4], b[4];
#pragma unroll
        for (int mf = 0; mf < 4; ++mf)
            a[mf] = *(const s16x8*)&As[(wm * 64 + mf * 16 + frag_r) * 32 + kslot];
#pragma unroll
        for (int nf = 0; nf < 4; ++nf)
            b[nf] = *(const s16x8*)&Bs[(wn * 64 + nf * 16 + frag_r) * 32 + kslot];
#pragma unroll
        for (int mf = 0; mf < 4; ++mf)
#pragma unroll
            for (int nf = 0; nf < 4; ++nf)
                acc[mf][nf] = __builtin_amdgcn_mfma_f32_16x16x32_bf16(
                    a[mf], b[nf], acc[mf][nf], 0, 0, 0);
    }

    // ---- epilogue: C frag layout col=lane&15, row=(lane>>4)*4+reg ----
    const int col_local = wn * 64 + (l & 15);
    const int rbase = wm * 64 + (l >> 4) * 4;
#pragma unroll
    for (int nf = 0; nf < 4; ++nf) {
        const int n = n0 + col_local + nf * 16;
        const float bs = bias[n];
#pragma unroll
        for (int mf = 0; mf < 4; ++mf) {
            const f32x4 v = acc[mf][nf];
#pragma unroll
            for (int rr = 0; rr < 4; ++rr) {
                const int m = m0 + rbase + mf * 16 + rr;
                const float o = v[rr] + bs;
                if (OMODE == 0) {
                    ((float*)Cp)[(size_t)m * ldc + n] = o;
                } else if (OMODE == 1) {
                    ((short*)Cp)[(size_t)m * ldc + n] = f2bf(o);
                } else {
                    const int bb = m >> 14, pix = m & (HW_ - 1);
                    const int h = n >> 5, d = n & 31;
                    ((short*)Cp)[((size_t)(bb * NH_ + h) * HW_ + pix) * HD_ + d] = f2bf(o);
                }
            }
        }
    }
}

// ---------------------------------------------------------------------------
// Sampling: one block per query. thread = (h = tid>>5, d = tid&31).
// oa row stride 128 (f32); vproj bf16; samp bf16.
// ---------------------------------------------------------------------------
__global__ __launch_bounds__(256)
void sample_kernel(const float* __restrict__ oa,    // [B*NQ, 128] (96 used)
                   const float* __restrict__ ref,   // [B*NQ, 2]
                   const short* __restrict__ vproj, // [B*NH, HW, HD] bf16
                   short* __restrict__ samp)        // [B*NQ, 256] bf16
{
    __shared__ float s_oa[96];
    __shared__ float s_ref[2];
    const int q = blockIdx.x;
    const int tid = threadIdx.x;
    if (tid < 96) s_oa[tid] = oa[(size_t)q * 128 + tid];
    if (tid < 2)  s_ref[tid] = ref[(size_t)q * 2 + tid];
    __syncthreads();

    const int d = tid & 31;
    const int h = tid >> 5;
    const int b = q >> 13;
    const short* vh = vproj + (size_t)(b * NH_ + h) * (HW_ * HD_);

    const float l0 = s_oa[64 + h * 4 + 0];
    const float l1 = s_oa[64 + h * 4 + 1];
    const float l2 = s_oa[64 + h * 4 + 2];
    const float l3 = s_oa[64 + h * 4 + 3];
    const float mx = fmaxf(fmaxf(l0, l1), fmaxf(l2, l3));
    const float e0 = __expf(l0 - mx), e1 = __expf(l1 - mx);
    const float e2 = __expf(l2 - mx), e3 = __expf(l3 - mx);
    const float inv = 1.f / (e0 + e1 + e2 + e3);
    const float aw[4] = { e0 * inv, e1 * inv, e2 * inv, e3 * inv };

    const float rx = s_ref[0], ry = s_ref[1];
    float acc = 0.f;
#pragma unroll
    for (int p = 0; p < 4; ++p) {
        const float ox = s_oa[h * 8 + p * 2 + 0] * (0.1f / (float)W_);
        const float oy = s_oa[h * 8 + p * 2 + 1] * (0.1f / (float)H_);
        const float lx = fminf(fmaxf(rx + ox, 0.f), 1.f);
        const float ly = fminf(fmaxf(ry + oy, 0.f), 1.f);
        const float gx = fminf(fmaxf(lx * (float)W_ - 0.5f, 0.f), (float)(W_ - 1));
        const float gy = fminf(fmaxf(ly * (float)H_ - 0.5f, 0.f), (float)(H_ - 1));
        const float x0f = floorf(gx), y0f = floorf(gy);
        const float fx = gx - x0f, fy = gy - y0f;
        const int x0 = (int)x0f, y0 = (int)y0f;
        const int x1 = min(x0 + 1, W_ - 1), y1 = min(y0 + 1, H_ - 1);
        const short* r0 = vh + (size_t)(y0 * W_) * HD_;
        const short* r1 = vh + (size_t)(y1 * W_) * HD_;
        const float v00 = bf2f(r0[x0 * HD_ + d]);
        const float v10 = bf2f(r0[x1 * HD_ + d]);
        const float v01 = bf2f(r1[x0 * HD_ + d]);
        const float v11 = bf2f(r1[x1 * HD_ + d]);
        const float vx0 = v00 + fx * (v10 - v00);
        const float vx1 = v01 + fx * (v11 - v01);
        acc += aw[p] * (vx0 + fy * (vx1 - vx0));
    }
    samp[(size_t)q * 256 + h * HD_ + d] = f2bf(acc);
}

// ---------------------------------------------------------------------------
extern "C" void kernel_launch(void* const* d_in, const int* in_sizes, int n_in,
                              void* d_out, int out_size, void* d_ws, size_t ws_size,
                              hipStream_t stream)
{
    const float* query  = (const float*)d_in[0];
    const float* refpt  = (const float*)d_in[1];
    const float* value  = (const float*)d_in[2];
    const float* W_off  = (const float*)d_in[3];
    const float* b_off  = (const float*)d_in[4];
    const float* W_attn = (const float*)d_in[5];
    const float* b_attn = (const float*)d_in[6];
    const float* W_val  = (const float*)d_in[7];
    const float* b_val  = (const float*)d_in[8];
    const float* W_out  = (const float*)d_in[9];
    const float* b_out  = (const float*)d_in[10];
    float* out = (float*)d_out;

    char* ws = (char*)d_ws;
    short* vproj  = (short*)ws;                                   // 32 MiB bf16
    short* samp   = (short*)(ws + (size_t)32 * 1024 * 1024);      // 16 MiB bf16
    float* oa     = (float*)(ws + (size_t)48 * 1024 * 1024);      // 16 MiB f32 [32768][128]
    short* BtVal  = (short*)(ws + (size_t)64 * 1024 * 1024);      // 128 KiB
    short* BtOut  = BtVal + 256 * 256;                            // 128 KiB
    short* BtOA   = BtOut + 256 * 256;                            // 64 KiB
    float* biasOA = (float*)(BtOA + 128 * 256);                   // 512 B

    prep_kernel<<<640, 256, 0, stream>>>(W_val, W_out, W_off, W_attn,
                                         b_off, b_attn, BtVal, BtOut, BtOA, biasOA);

    // K1: vproj = permute(value @ W_val + b_val), bf16 out
    gemm_mfma<1, 2><<<dim3((B_ * HW_) / 128, 2), 256, 0, stream>>>(
        value, BtVal, b_val, vproj, 0);

    // K2a: oa = query @ [W_off | W_attn | 0] + bias, f32 out, ldc=128
    gemm_mfma<1, 0><<<dim3((B_ * NQ_) / 128, 1), 256, 0, stream>>>(
        query, BtOA, biasOA, oa, 128);

    // K2b: bilinear deformable sampling -> samp (bf16)
    sample_kernel<<<B_ * NQ_, 256, 0, stream>>>(oa, refpt, vproj, samp);

    // K3: out = samp @ W_out + b_out, f32
    gemm_mfma<0, 0><<<dim3((B_ * NQ_) / 128, 2), 256, 0, stream>>>(
        samp, BtOut, b_out, out, 256);
}

// Round 3
// 87.948 us; speedup vs baseline: 2.8865x; 1.2652x over previous
//
#include <hip/hip_runtime.h>
#include <cstddef>

#define B_   4
#define NQ_  8192
#define C_   256
#define H_   128
#define W_   128
#define HW_  (H_ * W_)
#define NH_  8
#define NP_  4
#define HD_  32

typedef __attribute__((ext_vector_type(8))) short s16x8;
typedef __attribute__((ext_vector_type(4))) float f32x4;

__device__ __forceinline__ short f2bf(float x) {
    unsigned u = __float_as_uint(x);
    unsigned r = (u + 0x7FFFu + ((u >> 16) & 1u)) >> 16;
    return (short)r;
}
__device__ __forceinline__ void gload_lds16(const void* g, void* l) {
    __builtin_amdgcn_global_load_lds(
        (const __attribute__((address_space(1))) void*)g,
        (__attribute__((address_space(3))) void*)l, 16, 0, 0);
}

// ---------------------------------------------------------------------------
// Prep: transposed bf16 weights Bt[n][k] (+ composite off|attn matrix padded
// to 128 cols, and its padded bias).
// ---------------------------------------------------------------------------
__global__ void prep_kernel(const float* __restrict__ Wv, const float* __restrict__ Wo,
                            const float* __restrict__ Woff, const float* __restrict__ Wattn,
                            const float* __restrict__ boff, const float* __restrict__ battn,
                            short* __restrict__ BtVal, short* __restrict__ BtOut,
                            short* __restrict__ BtOA, float* __restrict__ biasOA)
{
    const int b = blockIdx.x, t = threadIdx.x;   // t = k index, 0..255
    if (b < 256) {
        const int n = b;
        BtVal[(size_t)n * 256 + t] = f2bf(Wv[(size_t)t * 256 + n]);
    } else if (b < 512) {
        const int n = b - 256;
        BtOut[(size_t)n * 256 + t] = f2bf(Wo[(size_t)t * 256 + n]);
    } else {
        const int n = b - 512;   // 0..127
        float v = (n < 64) ? Woff[(size_t)t * 64 + n]
                           : (n < 96 ? Wattn[(size_t)t * 32 + (n - 64)] : 0.f);
        BtOA[(size_t)n * 256 + t] = f2bf(v);
        if (t == 0) biasOA[n] = (n < 64) ? boff[n] : (n < 96 ? battn[n - 64] : 0.f);
    }
}

// ---------------------------------------------------------------------------
// bf16 MFMA GEMM, K=256 fixed. 128x128 tile, 4 waves (2x2 of 64x64), BK=32.
// AMODE 0: A bf16 via global_load_lds. AMODE 1: A f32, reg-staged + convert.
// OMODE 0: f32 C; OMODE 2: bf16 vproj-permute store.
// ---------------------------------------------------------------------------
template<int AMODE, int OMODE>
__global__ __launch_bounds__(256)
void gemm_mfma(const void* __restrict__ Ap, const short* __restrict__ Bt,
               const float* __restrict__ bias, void* __restrict__ Cp, int ldc)
{
    __shared__ short As[128 * 32];
    __shared__ short Bs[128 * 32];
    const int tid = threadIdx.x;
    const int l = tid & 63;
    const int w = tid >> 6;
    const int wm = w >> 1, wn = w & 1;
    const int m0 = blockIdx.x * 128;
    const int n0 = blockIdx.y * 128;

    f32x4 acc[4][4];
#pragma unroll
    for (int i = 0; i < 4; ++i)
#pragma unroll
        for (int j = 0; j < 4; ++j) acc[i][j] = (f32x4)0.f;

    const int frag_r = l & 15;
    const int kslot  = (l >> 4) * 8;

    for (int k0 = 0; k0 < 256; k0 += 32) {
        __syncthreads();
#pragma unroll
        for (int r = 0; r < 2; ++r) {
            const int i = r * 256 + tid;
            const int row = i >> 2, cb = (i & 3) * 8;
            gload_lds16(&Bt[(size_t)(n0 + row) * 256 + k0 + cb],
                        (char*)Bs + r * 4096 + w * 1024);
        }
        if (AMODE == 0) {
            const short* A16 = (const short*)Ap;
#pragma unroll
            for (int r = 0; r < 2; ++r) {
                const int i = r * 256 + tid;
                const int row = i >> 2, cb = (i & 3) * 8;
                gload_lds16(&A16[(size_t)(m0 + row) * 256 + k0 + cb],
                            (char*)As + r * 4096 + w * 1024);
            }
        } else {
            const float* Af = (const float*)Ap;
            const int row = tid >> 1, half = tid & 1;
            const float* src = &Af[(size_t)(m0 + row) * 256 + k0 + half * 16];
            float4 f0 = ((const float4*)src)[0];
            float4 f1 = ((const float4*)src)[1];
            float4 f2 = ((const float4*)src)[2];
            float4 f3 = ((const float4*)src)[3];
            union { short s[8]; s16x8 v; } p0, p1;
            p0.s[0]=f2bf(f0.x); p0.s[1]=f2bf(f0.y); p0.s[2]=f2bf(f0.z); p0.s[3]=f2bf(f0.w);
            p0.s[4]=f2bf(f1.x); p0.s[5]=f2bf(f1.y); p0.s[6]=f2bf(f1.z); p0.s[7]=f2bf(f1.w);
            p1.s[0]=f2bf(f2.x); p1.s[1]=f2bf(f2.y); p1.s[2]=f2bf(f2.z); p1.s[3]=f2bf(f2.w);
            p1.s[4]=f2bf(f3.x); p1.s[5]=f2bf(f3.y); p1.s[6]=f2bf(f3.z); p1.s[7]=f2bf(f3.w);
            *(s16x8*)&As[row * 32 + half * 16]     = p0.v;
            *(s16x8*)&As[row * 32 + half * 16 + 8] = p1.v;
        }
        __syncthreads();
        s16x8 a[4], b[4];
#pragma unroll
        for (int mf = 0; mf < 4; ++mf)
            a[mf] = *(const s16x8*)&As[(wm * 64 + mf * 16 + frag_r) * 32 + kslot];
#pragma unroll
        for (int nf = 0; nf < 4; ++nf)
            b[nf] = *(const s16x8*)&Bs[(wn * 64 + nf * 16 + frag_r) * 32 + kslot];
#pragma unroll
        for (int mf = 0; mf < 4; ++mf)
#pragma unroll
            for (int nf = 0; nf < 4; ++nf)
                acc[mf][nf] = __builtin_amdgcn_mfma_f32_16x16x32_bf16(
                    a[mf], b[nf], acc[mf][nf], 0, 0, 0);
    }

    const int col_local = wn * 64 + (l & 15);
    const int rbase = wm * 64 + (l >> 4) * 4;
#pragma unroll
    for (int nf = 0; nf < 4; ++nf) {
        const int n = n0 + col_local + nf * 16;
        const float bs = bias[n];
#pragma unroll
        for (int mf = 0; mf < 4; ++mf) {
            const f32x4 v = acc[mf][nf];
#pragma unroll
            for (int rr = 0; rr < 4; ++rr) {
                const int m = m0 + rbase + mf * 16 + rr;
                const float o = v[rr] + bs;
                if (OMODE == 0) {
                    ((float*)Cp)[(size_t)m * ldc + n] = o;
                } else {
                    const int bb = m >> 14, pix = m & (HW_ - 1);
                    const int h = n >> 5, d = n & 31;
                    ((short*)Cp)[((size_t)(bb * NH_ + h) * HW_ + pix) * HD_ + d] = f2bf(o);
                }
            }
        }
    }
}

// ---------------------------------------------------------------------------
// Sampling, v2: block = 256 threads = 2 queries.
// Phase 1 (tid<64): lane = (q'=tid>>5, hp=tid&31) computes softmax (4-lane
// shfl reduce), corner indices, and pre-multiplied corner weights -> LDS.
// Phase 2: 128 threads per query, thread=(h=t>>4, d0=(t&15)*2), gathers
// bf16x2 per corner (uint load), 4 FMAs per corner pair.
// ---------------------------------------------------------------------------
__global__ __launch_bounds__(256)
void sample_kernel(const float* __restrict__ oa,    // [B*NQ, 128] (96 used)
                   const float* __restrict__ ref,   // [B*NQ, 2]
                   const short* __restrict__ vproj, // [B*NH, HW, HD] bf16
                   short* __restrict__ samp)        // [B*NQ, 256] bf16
{
    __shared__ int4   s_idx[2][32];
    __shared__ float4 s_w[2][32];
    const int tid = threadIdx.x;
    const int q0 = blockIdx.x * 2;

    if (tid < 64) {
        const int qq = tid >> 5;          // 0..1
        const int hp = tid & 31;          // (h,p)
        const int h = hp >> 2, p = hp & 3;
        const int q = q0 + qq;
        const float logit = oa[(size_t)q * 128 + 64 + h * 4 + p];
        // softmax over the 4 lanes sharing h
        float mx = fmaxf(logit, __shfl_xor(logit, 1));
        mx = fmaxf(mx, __shfl_xor(mx, 2));
        float e = __expf(logit - mx);
        float s = e + __shfl_xor(e, 1);
        s += __shfl_xor(s, 2);
        const float aw = e / s;

        const float ox = oa[(size_t)q * 128 + h * 8 + p * 2 + 0] * (0.1f / (float)W_);
        const float oy = oa[(size_t)q * 128 + h * 8 + p * 2 + 1] * (0.1f / (float)H_);
        const float lx = fminf(fmaxf(ref[(size_t)q * 2 + 0] + ox, 0.f), 1.f);
        const float ly = fminf(fmaxf(ref[(size_t)q * 2 + 1] + oy, 0.f), 1.f);
        const float gx = fminf(fmaxf(lx * (float)W_ - 0.5f, 0.f), (float)(W_ - 1));
        const float gy = fminf(fmaxf(ly * (float)H_ - 0.5f, 0.f), (float)(H_ - 1));
        const float x0f = floorf(gx), y0f = floorf(gy);
        const float fx = gx - x0f, fy = gy - y0f;
        const int x0 = (int)x0f, y0 = (int)y0f;
        const int x1 = min(x0 + 1, W_ - 1), y1 = min(y0 + 1, H_ - 1);
        s_idx[qq][hp] = make_int4((y0 * W_ + x0) * HD_, (y0 * W_ + x1) * HD_,
                                  (y1 * W_ + x0) * HD_, (y1 * W_ + x1) * HD_);
        const float gx1 = 1.f - fx, gy1 = 1.f - fy;
        s_w[qq][hp] = make_float4(aw * gx1 * gy1, aw * fx * gy1,
                                  aw * gx1 * fy,  aw * fx * fy);
    }
    __syncthreads();

    const int qq = tid >> 7;
    const int t = tid & 127;
    const int h = t >> 4;
    const int d0 = (t & 15) * 2;
    const int q = q0 + qq;
    const int b = q >> 13;
    const short* vh = vproj + (size_t)(b * NH_ + h) * (HW_ * HD_) + d0;

    float a0 = 0.f, a1 = 0.f;
#pragma unroll
    for (int p = 0; p < 4; ++p) {
        const int4   ii = s_idx[qq][h * 4 + p];
        const float4 ww = s_w[qq][h * 4 + p];
        unsigned v;
        v = *(const unsigned*)&vh[ii.x];
        a0 = fmaf(ww.x, __uint_as_float(v << 16), a0);
        a1 = fmaf(ww.x, __uint_as_float(v & 0xFFFF0000u), a1);
        v = *(const unsigned*)&vh[ii.y];
        a0 = fmaf(ww.y, __uint_as_float(v << 16), a0);
        a1 = fmaf(ww.y, __uint_as_float(v & 0xFFFF0000u), a1);
        v = *(const unsigned*)&vh[ii.z];
        a0 = fmaf(ww.z, __uint_as_float(v << 16), a0);
        a1 = fmaf(ww.z, __uint_as_float(v & 0xFFFF0000u), a1);
        v = *(const unsigned*)&vh[ii.w];
        a0 = fmaf(ww.w, __uint_as_float(v << 16), a0);
        a1 = fmaf(ww.w, __uint_as_float(v & 0xFFFF0000u), a1);
    }
    const unsigned lo = (unsigned)(unsigned short)f2bf(a0);
    const unsigned hi = (unsigned)(unsigned short)f2bf(a1);
    ((unsigned*)samp)[((size_t)q * 256 + h * HD_ + d0) >> 1] = lo | (hi << 16);
}

// ---------------------------------------------------------------------------
extern "C" void kernel_launch(void* const* d_in, const int* in_sizes, int n_in,
                              void* d_out, int out_size, void* d_ws, size_t ws_size,
                              hipStream_t stream)
{
    const float* query  = (const float*)d_in[0];
    const float* refpt  = (const float*)d_in[1];
    const float* value  = (const float*)d_in[2];
    const float* W_off  = (const float*)d_in[3];
    const float* b_off  = (const float*)d_in[4];
    const float* W_attn = (const float*)d_in[5];
    const float* b_attn = (const float*)d_in[6];
    const float* W_val  = (const float*)d_in[7];
    const float* b_val  = (const float*)d_in[8];
    const float* W_out  = (const float*)d_in[9];
    const float* b_out  = (const float*)d_in[10];
    float* out = (float*)d_out;

    char* ws = (char*)d_ws;
    short* vproj  = (short*)ws;                                   // 32 MiB bf16
    short* samp   = (short*)(ws + (size_t)32 * 1024 * 1024);      // 16 MiB bf16
    float* oa     = (float*)(ws + (size_t)48 * 1024 * 1024);      // 16 MiB f32 [32768][128]
    short* BtVal  = (short*)(ws + (size_t)64 * 1024 * 1024);      // 128 KiB
    short* BtOut  = BtVal + 256 * 256;                            // 128 KiB
    short* BtOA   = BtOut + 256 * 256;                            // 64 KiB
    float* biasOA = (float*)(BtOA + 128 * 256);                   // 512 B

    prep_kernel<<<640, 256, 0, stream>>>(W_val, W_out, W_off, W_attn,
                                         b_off, b_attn, BtVal, BtOut, BtOA, biasOA);

    // K1: vproj = permute(value @ W_val + b_val), bf16 out
    gemm_mfma<1, 2><<<dim3((B_ * HW_) / 128, 2), 256, 0, stream>>>(
        value, BtVal, b_val, vproj, 0);

    // K2a: oa = query @ [W_off | W_attn | 0] + bias, f32 out, ldc=128
    gemm_mfma<1, 0><<<dim3((B_ * NQ_) / 128, 1), 256, 0, stream>>>(
        query, BtOA, biasOA, oa, 128);

    // K2b: bilinear deformable sampling -> samp (bf16)
    sample_kernel<<<(B_ * NQ_) / 2, 256, 0, stream>>>(oa, refpt, vproj, samp);

    // K3: out = samp @ W_out + b_out, f32
    gemm_mfma<0, 0><<<dim3((B_ * NQ_) / 128, 2), 256, 0, stream>>>(
        samp, BtOut, b_out, out, 256);
}

// Round 4
// 84.640 us; speedup vs baseline: 2.9993x; 1.0391x over previous
//
#include <hip/hip_runtime.h>
#include <cstddef>

#define B_   4
#define NQ_  8192
#define C_   256
#define H_   128
#define W_   128
#define HW_  (H_ * W_)
#define NH_  8
#define NP_  4
#define HD_  32

typedef __attribute__((ext_vector_type(8))) short s16x8;
typedef __attribute__((ext_vector_type(4))) float f32x4;

__device__ __forceinline__ short f2bf(float x) {
    unsigned u = __float_as_uint(x);
    unsigned r = (u + 0x7FFFu + ((u >> 16) & 1u)) >> 16;
    return (short)r;
}
__device__ __forceinline__ void gload_lds16(const void* g, void* l) {
    __builtin_amdgcn_global_load_lds(
        (const __attribute__((address_space(1))) void*)g,
        (__attribute__((address_space(3))) void*)l, 16, 0, 0);
}

// ---------------------------------------------------------------------------
// Prep: transposed bf16 weights Bt[n][k] (+ composite off|attn matrix padded
// to 128 cols, and its padded bias).
// ---------------------------------------------------------------------------
__global__ void prep_kernel(const float* __restrict__ Wv, const float* __restrict__ Wo,
                            const float* __restrict__ Woff, const float* __restrict__ Wattn,
                            const float* __restrict__ boff, const float* __restrict__ battn,
                            short* __restrict__ BtVal, short* __restrict__ BtOut,
                            short* __restrict__ BtOA, float* __restrict__ biasOA)
{
    const int b = blockIdx.x, t = threadIdx.x;   // t = k index, 0..255
    if (b < 256) {
        const int n = b;
        BtVal[(size_t)n * 256 + t] = f2bf(Wv[(size_t)t * 256 + n]);
    } else if (b < 512) {
        const int n = b - 256;
        BtOut[(size_t)n * 256 + t] = f2bf(Wo[(size_t)t * 256 + n]);
    } else {
        const int n = b - 512;   // 0..127
        float v = (n < 64) ? Woff[(size_t)t * 64 + n]
                           : (n < 96 ? Wattn[(size_t)t * 32 + (n - 64)] : 0.f);
        BtOA[(size_t)n * 256 + t] = f2bf(v);
        if (t == 0) biasOA[n] = (n < 64) ? boff[n] : (n < 96 ? battn[n - 64] : 0.f);
    }
}

// ---------------------------------------------------------------------------
// 2-phase double-buffered bf16 MFMA GEMM body, K=256 fixed (8 steps of BK=32).
// 128x128 tile, 4 waves (2x2 of 64x64), mfma_f32_16x16x32_bf16.
// Per K-step: issue stage(k+1) into buf^1, ds_read+MFMA from buf, then one
// vmcnt-drain + barrier (inside __syncthreads). Stage latency hides under MFMA.
// AMODE 0: A bf16 via global_load_lds. AMODE 1: A f32, reg-loaded + converted.
// omode 0: f32 C[m*ldc+n]; omode 2: bf16 vproj-permute store.
// As/Bs: [2][128*32] shorts (8 KiB per buffer).
// ---------------------------------------------------------------------------
template<int AMODE>
__device__ __forceinline__ void gemm_body(
    const void* __restrict__ Ap, const short* __restrict__ Bt,
    const float* __restrict__ bias, void* __restrict__ Cp,
    int ldc, int omode, int m0, int n0, short* As, short* Bs)
{
    const int tid = threadIdx.x;
    const int l = tid & 63;
    const int w = tid >> 6;
    const int wm = w >> 1, wn = w & 1;

    f32x4 acc[4][4];
#pragma unroll
    for (int i = 0; i < 4; ++i)
#pragma unroll
        for (int j = 0; j < 4; ++j) acc[i][j] = (f32x4)0.f;

    const int frag_r = l & 15;
    const int kslot  = (l >> 4) * 8;
    const int arow = tid >> 1, ahalf = tid & 1;     // AMODE 1 staging
    const float* Af = (const float*)Ap;
    const short* A16 = (const short*)Ap;

    float4 fA0, fA1, fA2, fA3;                      // in-flight A (AMODE 1)

#define STAGE_B(k0, buf)                                                      \
    _Pragma("unroll")                                                         \
    for (int r = 0; r < 2; ++r) {                                             \
        const int i = r * 256 + tid;                                          \
        gload_lds16(&Bt[(size_t)(n0 + (i >> 2)) * 256 + (k0) + (i & 3) * 8],  \
                    (char*)Bs + (buf) * 8192 + r * 4096 + w * 1024);          \
    }
#define STAGE_A_LDS(k0, buf)                                                  \
    _Pragma("unroll")                                                         \
    for (int r = 0; r < 2; ++r) {                                             \
        const int i = r * 256 + tid;                                          \
        gload_lds16(&A16[(size_t)(m0 + (i >> 2)) * 256 + (k0) + (i & 3) * 8], \
                    (char*)As + (buf) * 8192 + r * 4096 + w * 1024);          \
    }
#define LOAD_A_REGS(k0)                                                       \
    {                                                                         \
        const float* src = &Af[(size_t)(m0 + arow) * 256 + (k0) + ahalf * 16];\
        fA0 = ((const float4*)src)[0];                                        \
        fA1 = ((const float4*)src)[1];                                        \
        fA2 = ((const float4*)src)[2];                                        \
        fA3 = ((const float4*)src)[3];                                        \
    }
#define WRITE_A(buf)                                                          \
    {                                                                         \
        union { short s[8]; s16x8 v; } p0, p1;                                \
        p0.s[0]=f2bf(fA0.x); p0.s[1]=f2bf(fA0.y); p0.s[2]=f2bf(fA0.z); p0.s[3]=f2bf(fA0.w); \
        p0.s[4]=f2bf(fA1.x); p0.s[5]=f2bf(fA1.y); p0.s[6]=f2bf(fA1.z); p0.s[7]=f2bf(fA1.w); \
        p1.s[0]=f2bf(fA2.x); p1.s[1]=f2bf(fA2.y); p1.s[2]=f2bf(fA2.z); p1.s[3]=f2bf(fA2.w); \
        p1.s[4]=f2bf(fA3.x); p1.s[5]=f2bf(fA3.y); p1.s[6]=f2bf(fA3.z); p1.s[7]=f2bf(fA3.w); \
        *(s16x8*)&As[(buf) * 4096 + arow * 32 + ahalf * 16]     = p0.v;       \
        *(s16x8*)&As[(buf) * 4096 + arow * 32 + ahalf * 16 + 8] = p1.v;       \
    }

    // ---- prologue: fill buffer 0 with K-step 0 ----
    STAGE_B(0, 0);
    if (AMODE == 0) { STAGE_A_LDS(0, 0); }
    else            { LOAD_A_REGS(0); WRITE_A(0); }
    __syncthreads();

#pragma unroll
    for (int k = 0; k < 8; ++k) {
        const int cur = k & 1, nxt = cur ^ 1;
        // ---- issue next-tile stage (latency hides under this step's MFMA) --
        if (k < 7) {
            STAGE_B((k + 1) * 32, nxt);
            if (AMODE == 0) { STAGE_A_LDS((k + 1) * 32, nxt); }
            else            { LOAD_A_REGS((k + 1) * 32); }
        }
        // ---- compute current tile ----
        s16x8 a[4], b[4];
#pragma unroll
        for (int mf = 0; mf < 4; ++mf)
            a[mf] = *(const s16x8*)&As[cur * 4096 + (wm * 64 + mf * 16 + frag_r) * 32 + kslot];
#pragma unroll
        for (int nf = 0; nf < 4; ++nf)
            b[nf] = *(const s16x8*)&Bs[cur * 4096 + (wn * 64 + nf * 16 + frag_r) * 32 + kslot];
#pragma unroll
        for (int mf = 0; mf < 4; ++mf)
#pragma unroll
            for (int nf = 0; nf < 4; ++nf)
                acc[mf][nf] = __builtin_amdgcn_mfma_f32_16x16x32_bf16(
                    a[mf], b[nf], acc[mf][nf], 0, 0, 0);
        // ---- finish staging next buffer, one barrier per step ----
        if (k < 7) {
            if (AMODE == 1) WRITE_A(nxt);   // waits on fA loads
            __syncthreads();                // drains vmcnt/lgkm, then barrier
        }
    }
#undef STAGE_B
#undef STAGE_A_LDS
#undef LOAD_A_REGS
#undef WRITE_A

    // ---- epilogue: C frag layout col=lane&15, row=(lane>>4)*4+reg ----
    const int col_local = wn * 64 + (l & 15);
    const int rbase = wm * 64 + (l >> 4) * 4;
    if (omode == 0) {
#pragma unroll
        for (int nf = 0; nf < 4; ++nf) {
            const int n = n0 + col_local + nf * 16;
            const float bs = bias[n];
#pragma unroll
            for (int mf = 0; mf < 4; ++mf) {
                const f32x4 v = acc[mf][nf];
#pragma unroll
                for (int rr = 0; rr < 4; ++rr)
                    ((float*)Cp)[(size_t)(m0 + rbase + mf * 16 + rr) * ldc + n] = v[rr] + bs;
            }
        }
    } else {
#pragma unroll
        for (int nf = 0; nf < 4; ++nf) {
            const int n = n0 + col_local + nf * 16;
            const float bs = bias[n];
            const int h = n >> 5, d = n & 31;
#pragma unroll
            for (int mf = 0; mf < 4; ++mf) {
                const f32x4 v = acc[mf][nf];
#pragma unroll
                for (int rr = 0; rr < 4; ++rr) {
                    const int m = m0 + rbase + mf * 16 + rr;
                    const int bb = m >> 14, pix = m & (HW_ - 1);
                    ((short*)Cp)[((size_t)(bb * NH_ + h) * HW_ + pix) * HD_ + d] = f2bf(v[rr] + bs);
                }
            }
        }
    }
}

// ---------------------------------------------------------------------------
// Merged K1 + K2a: blocks 0..1023 -> vproj GEMM; 1024..1279 -> off/attn GEMM.
// ---------------------------------------------------------------------------
__global__ __launch_bounds__(256, 4)
void gemm_k1k2a(const float* __restrict__ value, const short* __restrict__ BtVal,
                const float* __restrict__ b_val, short* __restrict__ vproj,
                const float* __restrict__ query, const short* __restrict__ BtOA,
                const float* __restrict__ biasOA, float* __restrict__ oa)
{
    __shared__ short As[2 * 4096];
    __shared__ short Bs[2 * 4096];
    const int bid = blockIdx.x;
    if (bid < 1024) {
        gemm_body<1>(value, BtVal, b_val, vproj, 0, 2,
                     (bid >> 1) * 128, (bid & 1) * 128, As, Bs);
    } else {
        gemm_body<1>(query, BtOA, biasOA, oa, 128, 0,
                     (bid - 1024) * 128, 0, As, Bs);
    }
}

// ---------------------------------------------------------------------------
// K3: out = samp @ W_out + b_out (A bf16 via global_load_lds)
// ---------------------------------------------------------------------------
__global__ __launch_bounds__(256, 4)
void gemm_k3(const short* __restrict__ samp, const short* __restrict__ BtOut,
             const float* __restrict__ b_out, float* __restrict__ out)
{
    __shared__ short As[2 * 4096];
    __shared__ short Bs[2 * 4096];
    gemm_body<0>(samp, BtOut, b_out, out, 256, 0,
                 (blockIdx.x >> 1) * 128, (blockIdx.x & 1) * 128, As, Bs);
}

// ---------------------------------------------------------------------------
// Sampling: block = 256 threads = 2 queries. Phase 1 (tid<64): softmax +
// corner indices + pre-multiplied weights -> LDS. Phase 2: (h, d-pair) gather.
// ---------------------------------------------------------------------------
__global__ __launch_bounds__(256)
void sample_kernel(const float* __restrict__ oa,    // [B*NQ, 128] (96 used)
                   const float* __restrict__ ref,   // [B*NQ, 2]
                   const short* __restrict__ vproj, // [B*NH, HW, HD] bf16
                   short* __restrict__ samp)        // [B*NQ, 256] bf16
{
    __shared__ int4   s_idx[2][32];
    __shared__ float4 s_w[2][32];
    const int tid = threadIdx.x;
    const int q0 = blockIdx.x * 2;

    if (tid < 64) {
        const int qq = tid >> 5;
        const int hp = tid & 31;
        const int h = hp >> 2, p = hp & 3;
        const int q = q0 + qq;
        const float logit = oa[(size_t)q * 128 + 64 + h * 4 + p];
        float mx = fmaxf(logit, __shfl_xor(logit, 1));
        mx = fmaxf(mx, __shfl_xor(mx, 2));
        float e = __expf(logit - mx);
        float s = e + __shfl_xor(e, 1);
        s += __shfl_xor(s, 2);
        const float aw = e / s;

        const float ox = oa[(size_t)q * 128 + h * 8 + p * 2 + 0] * (0.1f / (float)W_);
        const float oy = oa[(size_t)q * 128 + h * 8 + p * 2 + 1] * (0.1f / (float)H_);
        const float lx = fminf(fmaxf(ref[(size_t)q * 2 + 0] + ox, 0.f), 1.f);
        const float ly = fminf(fmaxf(ref[(size_t)q * 2 + 1] + oy, 0.f), 1.f);
        const float gx = fminf(fmaxf(lx * (float)W_ - 0.5f, 0.f), (float)(W_ - 1));
        const float gy = fminf(fmaxf(ly * (float)H_ - 0.5f, 0.f), (float)(H_ - 1));
        const float x0f = floorf(gx), y0f = floorf(gy);
        const float fx = gx - x0f, fy = gy - y0f;
        const int x0 = (int)x0f, y0 = (int)y0f;
        const int x1 = min(x0 + 1, W_ - 1), y1 = min(y0 + 1, H_ - 1);
        s_idx[qq][hp] = make_int4((y0 * W_ + x0) * HD_, (y0 * W_ + x1) * HD_,
                                  (y1 * W_ + x0) * HD_, (y1 * W_ + x1) * HD_);
        const float gx1 = 1.f - fx, gy1 = 1.f - fy;
        s_w[qq][hp] = make_float4(aw * gx1 * gy1, aw * fx * gy1,
                                  aw * gx1 * fy,  aw * fx * fy);
    }
    __syncthreads();

    const int qq = tid >> 7;
    const int t = tid & 127;
    const int h = t >> 4;
    const int d0 = (t & 15) * 2;
    const int q = q0 + qq;
    const int b = q >> 13;
    const short* vh = vproj + (size_t)(b * NH_ + h) * (HW_ * HD_) + d0;

    float a0 = 0.f, a1 = 0.f;
#pragma unroll
    for (int p = 0; p < 4; ++p) {
        const int4   ii = s_idx[qq][h * 4 + p];
        const float4 ww = s_w[qq][h * 4 + p];
        unsigned v;
        v = *(const unsigned*)&vh[ii.x];
        a0 = fmaf(ww.x, __uint_as_float(v << 16), a0);
        a1 = fmaf(ww.x, __uint_as_float(v & 0xFFFF0000u), a1);
        v = *(const unsigned*)&vh[ii.y];
        a0 = fmaf(ww.y, __uint_as_float(v << 16), a0);
        a1 = fmaf(ww.y, __uint_as_float(v & 0xFFFF0000u), a1);
        v = *(const unsigned*)&vh[ii.z];
        a0 = fmaf(ww.z, __uint_as_float(v << 16), a0);
        a1 = fmaf(ww.z, __uint_as_float(v & 0xFFFF0000u), a1);
        v = *(const unsigned*)&vh[ii.w];
        a0 = fmaf(ww.w, __uint_as_float(v << 16), a0);
        a1 = fmaf(ww.w, __uint_as_float(v & 0xFFFF0000u), a1);
    }
    const unsigned lo = (unsigned)(unsigned short)f2bf(a0);
    const unsigned hi = (unsigned)(unsigned short)f2bf(a1);
    ((unsigned*)samp)[((size_t)q * 256 + h * HD_ + d0) >> 1] = lo | (hi << 16);
}

// ---------------------------------------------------------------------------
extern "C" void kernel_launch(void* const* d_in, const int* in_sizes, int n_in,
                              void* d_out, int out_size, void* d_ws, size_t ws_size,
                              hipStream_t stream)
{
    const float* query  = (const float*)d_in[0];
    const float* refpt  = (const float*)d_in[1];
    const float* value  = (const float*)d_in[2];
    const float* W_off  = (const float*)d_in[3];
    const float* b_off  = (const float*)d_in[4];
    const float* W_attn = (const float*)d_in[5];
    const float* b_attn = (const float*)d_in[6];
    const float* W_val  = (const float*)d_in[7];
    const float* b_val  = (const float*)d_in[8];
    const float* W_out  = (const float*)d_in[9];
    const float* b_out  = (const float*)d_in[10];
    float* out = (float*)d_out;

    char* ws = (char*)d_ws;
    short* vproj  = (short*)ws;                                   // 32 MiB bf16
    short* samp   = (short*)(ws + (size_t)32 * 1024 * 1024);      // 16 MiB bf16
    float* oa     = (float*)(ws + (size_t)48 * 1024 * 1024);      // 16 MiB f32 [32768][128]
    short* BtVal  = (short*)(ws + (size_t)64 * 1024 * 1024);      // 128 KiB
    short* BtOut  = BtVal + 256 * 256;                            // 128 KiB
    short* BtOA   = BtOut + 256 * 256;                            // 64 KiB
    float* biasOA = (float*)(BtOA + 128 * 256);                   // 512 B

    prep_kernel<<<640, 256, 0, stream>>>(W_val, W_out, W_off, W_attn,
                                         b_off, b_attn, BtVal, BtOut, BtOA, biasOA);

    // K1 (vproj) + K2a (off/attn) merged
    gemm_k1k2a<<<1280, 256, 0, stream>>>(value, BtVal, b_val, vproj,
                                         query, BtOA, biasOA, oa);

    // K2b: bilinear deformable sampling -> samp (bf16)
    sample_kernel<<<(B_ * NQ_) / 2, 256, 0, stream>>>(oa, refpt, vproj, samp);

    // K3: out = samp @ W_out + b_out, f32
    gemm_k3<<<512, 256, 0, stream>>>(samp, BtOut, b_out, out);
}